// Round 2
// baseline (312.768 us; speedup 1.0000x reference)
//
#include <hip/hip_runtime.h>
#include <hip/hip_bf16.h>
#include <math.h>

#define BLK 64
#define EPB 16            // elements per block (one wave)
#define NF 32
#define THIST 15
#define CFWS 20           // cfwP row stride in f32: 80B (16B-aligned for b128);
                          // 4s*20 -> bank offset 16s%32 = {0,16,0,16} -> 2-way (free)

typedef __attribute__((ext_vector_type(8))) short s16x8;  // 8 bf16 = 4 VGPRs
typedef __attribute__((ext_vector_type(4))) float f32x4;

union frag_u { s16x8 v; unsigned u[4]; };

// v_permlane32_swap + v_permlane16_swap: [a0,a1,a2,a3],[b0,b1,b2,b3] (16-lane
// groups) -> A=[a0,a2,b0,b2], B=[a1,a3,b1,b3]. Pure-VALU s-group redistribution.
#define SWAP3216(A, B) \
    asm("v_permlane32_swap_b32 %0, %1\n\tv_permlane16_swap_b32 %0, %1" \
        : "+v"(A), "+v"(B))

// raw v_rcp_f32 (~1 ulp) — __fdividef is the precise IEEE seq w/o -ffast-math
__device__ __forceinline__ float frcp(float x) {
    return __builtin_amdgcn_rcpf(x);
}
__device__ __forceinline__ float sigm(float x) {
    return frcp(1.0f + __expf(-x));
}
// tanh = 1 - 2/(e^{2x}+1); exact saturation
__device__ __forceinline__ float tanhfe(float x) {
    float e = __expf(2.0f * x);
    return fmaf(-2.0f, frcp(e + 1.0f), 1.0f);
}
__device__ __forceinline__ float bf16tof(unsigned short h) {
    return __uint_as_float(((unsigned)h) << 16);
}
__device__ __forceinline__ unsigned packbf2(float x0, float x1) {
    __hip_bfloat162 b = __float22bfloat162_rn(float2{x0, x1});
    union { __hip_bfloat162 b; unsigned u; } c; c.b = b; return c.u;
}
// split a PAIR of fp32 into packed-hi / packed-lo bf16 dwords (RNE, ~17-bit eff.)
__device__ __forceinline__ void bsplit2(float x0, float x1, unsigned& h2, unsigned& l2) {
    h2 = packbf2(x0, x1);
    float r0 = x0 - bf16tof((unsigned short)(h2 & 0xffffu));
    float r1 = x1 - bf16tof((unsigned short)(h2 >> 16));
    l2 = packbf2(r0, r1);
}

// wave sum over lanes L, L^16, L^32 (bit-identical to the shfl_xor chain),
// pure VALU (no LDS pipe / ds_swizzle latency)
__device__ __forceinline__ float xsum1632(float v) {
    float a = v, b = v;
    asm("v_permlane16_swap_b32 %0, %1" : "+v"(a), "+v"(b));
    float s2 = a + b;
    float p = s2, q = s2;
    asm("v_permlane32_swap_b32 %0, %1" : "+v"(p), "+v"(q));
    return p + q;
}

// P = F P F^T for the constant-accel F (dt=0.2), in place (uniform Riccati only)
__device__ __forceinline__ void fpft(float (&P)[6][6]) {
    const float dt = 0.2f, hd = 0.02f;
    #pragma unroll
    for (int j = 0; j < 6; ++j) {
        float a0 = P[0][j] + dt * P[1][j] + hd * P[2][j];
        float a1 = P[1][j] + dt * P[2][j];
        float a3 = P[3][j] + dt * P[4][j] + hd * P[5][j];
        float a4 = P[4][j] + dt * P[5][j];
        P[0][j] = a0; P[1][j] = a1; P[3][j] = a3; P[4][j] = a4;
    }
    #pragma unroll
    for (int i = 0; i < 6; ++i) {
        float a0 = P[i][0] + dt * P[i][1] + hd * P[i][2];
        float a1 = P[i][1] + dt * P[i][2];
        float a3 = P[i][3] + dt * P[i][4] + hd * P[i][5];
        float a4 = P[i][4] + dt * P[i][5];
        P[i][0] = a0; P[i][1] = a1; P[i][3] = a3; P[i][4] = a4;
    }
}

// ------------------------------- main kernel ---------------------------------
// R2 structure: h exchange is register-only (permlane swaps) — no LDS round
// trip, no per-step fence at all (pure dataflow + #pragma unroll 1 loops).
// History phase software-pipelined: X/feat of step t+1 (LSTM-independent)
// issue alongside MFMA/combine of step t. Bias rides as MFMA C-in.
__global__ __launch_bounds__(BLK, 2)
void kalman_lstm(const float* __restrict__ hist,
                 const float* __restrict__ psx, const float* __restrict__ psy,
                 const float* __restrict__ vsx, const float* __restrict__ vsy,
                 const float* __restrict__ asx, const float* __restrict__ asy,
                 const float* __restrict__ jerk, const float* __restrict__ coefG,
                 const float* __restrict__ GRv,
                 const float* __restrict__ cfW, const float* __restrict__ cfb,
                 const float* __restrict__ Wih, const float* __restrict__ Whh,
                 const float* __restrict__ bih, const float* __restrict__ bhh,
                 const float* __restrict__ coW, const float* __restrict__ cob,
                 float* __restrict__ out, int B, int len_pred)
{
    // cfW pair-interleaved: pair p -> [CFWS*p+0..5]=w(2p), [+6]=cfb(2p),
    // [+8..13]=w(2p+1), [+14]=cfb(2p+1). Broadcast across e-lanes, 2-way (free).
    __shared__ float    cfwP[16 * CFWS];
    __shared__ float    coT[NF * 4];      // [feat][gate]
    __shared__ float    kf[216];          // [t*12..+11]=K0,K1 (t<15); [180..215]=P_hist

    const int lane = threadIdx.x;
    const int e = lane & 15;              // element slot (MFMA n-index / D col)
    const int s = lane >> 4;              // quad (k-slice / D row group)
    const int b = blockIdx.x * EPB + e;

    // ---- LDS tables ----
    for (int i = lane; i < 16 * 16; i += BLK) {
        int p = i >> 4, c = i & 15;
        float v = 0.0f;
        if (c < 6)        v = cfW[(2 * p) * 6 + c];
        else if (c == 6)  v = cfb[2 * p];
        else if (c >= 8 && c < 14) v = cfW[(2 * p + 1) * 6 + (c - 8)];
        else if (c == 14) v = cfb[2 * p + 1];
        cfwP[p * CFWS + c] = v;
    }
    for (int i = lane; i < NF * 4; i += BLK) coT[i] = coW[(i & 3) * NF + (i >> 2)];

    const float dt = 0.2f, hd = 0.02f;
    const float g0 = dt * dt * dt / 6.0f, g1 = 0.02f, g2 = dt;
    float ga0 = g0 * tanhf(coefG[0]);
    float ga1 = g1 * tanhf(coefG[1]);
    float ga2 = g2 * tanhf(coefG[2]);
    float gb3 = g0 * tanhf(coefG[3]);
    float gb4 = g1 * tanhf(coefG[4]);
    float gb5 = g2 * tanhf(coefG[5]);

    // ---- batch-uniform Kalman-gain recursion (verbatim math; lane0 writes) ----
    {
        float j0 = jerk[0], j1 = jerk[1];
        float gr0 = GRv[0], gr1 = GRv[1];
        float R00 = gr0 * gr0, R01 = gr0 * gr1, R11 = gr1 * gr1;
        float qa[3] = {ga0 * j0, ga1 * j0, ga2 * j0};
        float qb[3] = {gb3 * j1, gb4 * j1, gb5 * j1};

        float Pk[6][6];
        #pragma unroll
        for (int i = 0; i < 6; ++i)
            #pragma unroll
            for (int j = 0; j < 6; ++j) Pk[i][j] = 0.0f;
        { float v;
          v = psx[0]; Pk[0][0] = v * v;
          v = vsx[0]; Pk[1][1] = v * v;
          v = asx[0]; Pk[2][2] = v * v;
          v = psy[0]; Pk[3][3] = v * v;
          v = vsy[0]; Pk[4][4] = v * v;
          v = asy[0]; Pk[5][5] = v * v; }

        #pragma unroll 1
        for (int t = 0; t < THIST; ++t) {
            fpft(Pk);
            #pragma unroll
            for (int i = 0; i < 3; ++i)
                #pragma unroll
                for (int j = 0; j < 3; ++j) {
                    Pk[i][j]         += qa[i] * qa[j];
                    Pk[3 + i][3 + j] += qb[i] * qb[j];
                }
            float S00 = Pk[0][0] + R00;
            float S01 = Pk[0][3] + R01;
            float S11 = Pk[3][3] + R11;
            float idet = 1.0f / (S00 * S11 - S01 * S01);
            float i00 =  S11 * idet, i01 = -S01 * idet, i11 = S00 * idet;
            float K0[6], K1[6];
            #pragma unroll
            for (int i = 0; i < 6; ++i) {
                K0[i] = Pk[i][0] * i00 + Pk[i][3] * i01;
                K1[i] = Pk[i][0] * i01 + Pk[i][3] * i11;
            }
            if (lane == 0) {
                #pragma unroll
                for (int i = 0; i < 6; ++i) {
                    kf[t * 12 + i]     = K0[i];
                    kf[t * 12 + 6 + i] = K1[i];
                }
            }
            #pragma unroll
            for (int i = 0; i < 6; ++i) {
                Pk[i][1] -= K0[1] * Pk[i][0] + K1[1] * Pk[i][3];
                Pk[i][2] -= K0[2] * Pk[i][0] + K1[2] * Pk[i][3];
                Pk[i][4] -= K0[4] * Pk[i][0] + K1[4] * Pk[i][3];
                Pk[i][5] -= K0[5] * Pk[i][0] + K1[5] * Pk[i][3];
                float t0 = Pk[i][0] - (K0[0] * Pk[i][0] + K1[0] * Pk[i][3]);
                float t3 = Pk[i][3] - (K0[3] * Pk[i][0] + K1[3] * Pk[i][3]);
                Pk[i][0] = t0; Pk[i][3] = t3;
            }
        }
        if (lane == 0) {
            #pragma unroll
            for (int i = 0; i < 6; ++i)
                #pragma unroll
                for (int j = 0; j < 6; ++j) kf[180 + i * 6 + j] = Pk[i][j];
        }
    }

    // ---- LSTM weights once into register fragments (hi/lo bf16 split) ----
    // A-operand: lane holds W[nt*16 + e][s*8 + j]
    s16x8 wih_h[8], wih_l[8], whh_h[8], whh_l[8];
    #pragma unroll
    for (int nt = 0; nt < 8; ++nt) {
        int base = (nt * 16 + e) * NF + s * 8;
        frag_u ih_h, ih_l, hh_h, hh_l;
        #pragma unroll
        for (int q = 0; q < 4; ++q) {
            bsplit2(Wih[base + 2 * q], Wih[base + 2 * q + 1], ih_h.u[q], ih_l.u[q]);
            bsplit2(Whh[base + 2 * q], Whh[base + 2 * q + 1], hh_h.u[q], hh_l.u[q]);
        }
        wih_h[nt] = ih_h.v; wih_l[nt] = ih_l.v;
        whh_h[nt] = hh_h.v; whh_l[nt] = hh_l.v;
    }

    // bias fragments (MFMA C-in): lane needs bias[nt*16 + 4s + r], r=0..3
    f32x4 biasF[8];
    #pragma unroll
    for (int nt = 0; nt < 8; ++nt) {
        int base = nt * 16 + 4 * s;
        f32x4 bi = *(const f32x4*)&bih[base];
        f32x4 bh = *(const f32x4*)&bhh[base];
        biasF[nt] = bi + bh;
    }

    // ---- Kalman state X (replicated across the 4 s-lanes of each element) ----
    const float2* hist2 = (const float2*)hist;
    float2 z0 = hist2[b];
    float2 z1 = hist2[B + b];
    float X0 = z0.x, X1 = (z1.x - z0.x) / dt, X2 = 0.0f;
    float X3 = (z1.y - z0.y) / dt, X4 = 0.0f, X5 = 0.0f;  // ref overwrites slot 3

    float creg[8], hn[8];
    #pragma unroll
    for (int j = 0; j < 8; ++j) { creg[j] = 0.0f; hn[j] = 0.0f; }
    s16x8 ah_h = (s16x8)0, ah_l = (s16x8)0;

    __syncthreads();   // one-time: tables visible

    // feat from explicit X values (pairs p=4s+q; conflict-free b128 broadcasts)
    auto compute_feat = [&](float x0, float x1, float x2, float x3, float x4,
                            float x5, frag_u& fh, frag_u& fl) {
        #pragma unroll
        for (int q = 0; q < 4; ++q) {
            int p16 = (4 * s + q) * CFWS;
            f32x4 wa = *(const f32x4*)&cfwP[p16];
            f32x4 wb = *(const f32x4*)&cfwP[p16 + 4];
            f32x4 wc = *(const f32x4*)&cfwP[p16 + 8];
            f32x4 wd = *(const f32x4*)&cfwP[p16 + 12];
            float a0 = wb[2] + wa[0] * x0 + wa[1] * x1 + wa[2] * x2
                             + wa[3] * x3 + wb[0] * x4 + wb[1] * x5;
            float a1 = wd[2] + wc[0] * x0 + wc[1] * x1 + wc[2] * x2
                             + wc[3] * x3 + wd[0] * x4 + wd[1] * x5;
            bsplit2(tanhfe(a0), tanhfe(a1), fh.u[q], fl.u[q]);
        }
    };

    // MFMA + gate combine + register h-exchange. Updates creg, hn, ah_h, ah_l.
    auto lstm_core = [&](const s16x8& afh, const s16x8& afl) {
        f32x4 acc[8];
        #pragma unroll
        for (int nt = 0; nt < 8; ++nt) {
            acc[nt] = __builtin_amdgcn_mfma_f32_16x16x32_bf16(wih_h[nt], afh, biasF[nt], 0, 0, 0);
            acc[nt] = __builtin_amdgcn_mfma_f32_16x16x32_bf16(wih_h[nt], afl, acc[nt], 0, 0, 0);
            acc[nt] = __builtin_amdgcn_mfma_f32_16x16x32_bf16(wih_l[nt], afh, acc[nt], 0, 0, 0);
            acc[nt] = __builtin_amdgcn_mfma_f32_16x16x32_bf16(whh_h[nt], ah_h, acc[nt], 0, 0, 0);
            acc[nt] = __builtin_amdgcn_mfma_f32_16x16x32_bf16(whh_h[nt], ah_l, acc[nt], 0, 0, 0);
            acc[nt] = __builtin_amdgcn_mfma_f32_16x16x32_bf16(whh_l[nt], ah_h, acc[nt], 0, 0, 0);
        }

        // combine: tiles {0,1}=i {2,3}=f {4,5}=g {6,7}=o; parity = feature block
        unsigned whx[2][2], wlx[2][2];   // [blk][rp] packed bf16 pair dwords
        #pragma unroll
        for (int blk = 0; blk < 2; ++blk) {
            float hv[4];
            #pragma unroll
            for (int r = 0; r < 4; ++r) {
                float gi = acc[0 + blk][r];
                float gf = acc[2 + blk][r];
                float gg = acc[4 + blk][r];
                float go = acc[6 + blk][r];
                float cn = sigm(gf) * creg[4 * blk + r] + sigm(gi) * tanhfe(gg);
                creg[4 * blk + r] = cn;
                hv[r] = sigm(go) * tanhfe(cn);
                hn[4 * blk + r] = hv[r];
            }
            #pragma unroll
            for (int rp = 0; rp < 2; ++rp)
                bsplit2(hv[2 * rp], hv[2 * rp + 1], whx[blk][rp], wlx[blk][rp]);
        }

        // register h-exchange: lane s holds pairs {2s,2s+1,8+2s,8+2s+1}; lane s'
        // needs {4s'..4s'+3}. Per (plane,rp): A=[p0,p2,p4,p6], B=[p8..p14] ->
        // swap32+swap16 -> A=[0,4,8,12]=word q=rp? no: q∈{rp, rp+2}:
        //   rp=0 -> words 0,2 ; rp=1 -> words 1,3.
        frag_u ahh, ahl;
        {
            unsigned A = whx[0][0], Bv = whx[1][0];
            SWAP3216(A, Bv); ahh.u[0] = A; ahh.u[2] = Bv;
        }
        {
            unsigned A = whx[0][1], Bv = whx[1][1];
            SWAP3216(A, Bv); ahh.u[1] = A; ahh.u[3] = Bv;
        }
        {
            unsigned A = wlx[0][0], Bv = wlx[1][0];
            SWAP3216(A, Bv); ahl.u[0] = A; ahl.u[2] = Bv;
        }
        {
            unsigned A = wlx[0][1], Bv = wlx[1][1];
            SWAP3216(A, Bv); ahl.u[1] = A; ahl.u[3] = Bv;
        }
        ah_h = ahh.v; ah_l = ahl.v;
    };

    // ------------- history phase (software-pipelined) -------------
    // X-recursion is LSTM-independent here: compute X_{t+1} + feat(X_{t+1})
    // BEFORE the step-t MFMA/combine so they fill its latency bubbles.
    frag_u afh_c, afl_c;
    compute_feat(X0, X1, X2, X3, X4, X5, afh_c, afl_c);
    float2 zc = z1;                       // z consumed by step t (index t+1)

    #pragma unroll 1
    for (int t = 0; t < THIST; ++t) {
        // prefetch z_{t+2} (t=14: redundant reload of z15, dead afterwards)
        int tn = (t + 2 < 15) ? (t + 2) : 15;
        float2 zn = hist2[(size_t)tn * B + b];

        // Kalman X update (uniform K from LDS) -> X_{t+1}
        f32x4 k0 = *(const f32x4*)&kf[t * 12];
        f32x4 k1 = *(const f32x4*)&kf[t * 12 + 4];
        f32x4 k2 = *(const f32x4*)&kf[t * 12 + 8];
        float nX0 = X0 + dt * X1 + hd * X2, nX1 = X1 + dt * X2, nX2 = X2;
        float nX3 = X3 + dt * X4 + hd * X5, nX4 = X4 + dt * X5, nX5 = X5;
        float y0 = zc.x - nX0, y1 = zc.y - nX3;
        nX0 += k0[0] * y0 + k1[2] * y1;
        nX1 += k0[1] * y0 + k1[3] * y1;
        nX2 += k0[2] * y0 + k2[0] * y1;
        nX3 += k0[3] * y0 + k2[1] * y1;
        nX4 += k1[0] * y0 + k2[2] * y1;
        nX5 += k1[1] * y0 + k2[3] * y1;

        frag_u afh_n, afl_n;
        compute_feat(nX0, nX1, nX2, nX3, nX4, nX5, afh_n, afl_n);

        lstm_core(afh_c.v, afl_c.v);      // step t (uses feat(X_t), h_{t-1})

        X0 = nX0; X1 = nX1; X2 = nX2; X3 = nX3; X4 = nX4; X5 = nX5;
        afh_c = afh_n; afl_c = afl_n;
        zc = zn;
    }
    // afh_c/afl_c now hold feat(X_15) — pred step 0 consumes it directly.

    // P becomes data-dependent only now; block-symmetric storage.
    float xx00 = kf[180], xx01 = kf[181], xx02 = kf[182],
          xx11 = kf[187], xx12 = kf[188], xx22 = kf[194];
    float yy00 = kf[201], yy01 = kf[202], yy02 = kf[203],
          yy11 = kf[208], yy12 = kf[209], yy22 = kf[214];
    float c00 = kf[183], c01 = kf[184], c02 = kf[185],
          c10 = kf[189], c11 = kf[190], c12 = kf[191],
          c20 = kf[195], c21 = kf[196], c22 = kf[197];

    // ---------------- prediction phase ----------------
    #pragma unroll 1
    for (int tp = 0; tp < len_pred; ++tp) {
        lstm_core(afh_c.v, afl_c.v);

        float cs0 = 0.0f, cs1 = 0.0f, cs2 = 0.0f, cs3 = 0.0f;
        #pragma unroll
        for (int blk = 0; blk < 2; ++blk)
            #pragma unroll
            for (int r = 0; r < 4; ++r) {
                int f = 16 * blk + 4 * s + r;
                f32x4 w = *(const f32x4*)&coT[f * 4];
                float hk = hn[4 * blk + r];
                cs0 += w[0] * hk;
                cs1 += w[1] * hk;
                cs2 += w[2] * hk;
                cs3 += w[3] * hk;
            }
        cs0 = xsum1632(cs0);
        cs1 = xsum1632(cs1);
        cs2 = xsum1632(cs2);
        cs3 = xsum1632(cs3);
        float cmd0 = cs0 + cob[0], cmd1 = cs1 + cob[1];
        float cmd2 = cs2 + cob[2], cmd3 = cs3 + cob[3];

        X0 = X0 + dt * X1 + hd * X2 + g0 * cmd0;
        X1 = X1 + dt * X2 + g1 * cmd0;
        X2 = X2 + g2 * cmd0;
        X3 = X3 + dt * X4 + hd * X5 + g0 * cmd1;
        X4 = X4 + dt * X5 + g1 * cmd1;
        X5 = X5 + g2 * cmd1;

        // feat for the next pred step (TRANS-heavy) — issued here so it
        // overlaps the FMA-heavy P-update below (separate pipes).
        if (tp + 1 < len_pred)
            compute_feat(X0, X1, X2, X3, X4, X5, afh_c, afl_c);

        // P = F P F^T + Gs Gs^T in block-symmetric form (69 FMA vs 132)
        float gs0 = ga0 * cmd2, gs1 = ga1 * cmd2, gs2 = ga2 * cmd2;
        float gs3 = gb3 * cmd3, gs4 = gb4 * cmd3, gs5 = gb5 * cmd3;
        {   // x-block (symmetric)
            float r00 = xx00 + dt * xx01 + hd * xx02;
            float r01 = xx01 + dt * xx11 + hd * xx12;
            float r02 = xx02 + dt * xx12 + hd * xx22;
            float r11 = xx11 + dt * xx12;
            float r12 = xx12 + dt * xx22;
            xx00 = r00 + dt * r01 + hd * r02;
            xx01 = r01 + dt * r02;
            xx02 = r02;
            xx11 = r11 + dt * r12;
            xx12 = r12;
            xx00 += gs0 * gs0; xx01 += gs0 * gs1; xx02 += gs0 * gs2;
            xx11 += gs1 * gs1; xx12 += gs1 * gs2; xx22 += gs2 * gs2;
        }
        {   // y-block (symmetric)
            float r00 = yy00 + dt * yy01 + hd * yy02;
            float r01 = yy01 + dt * yy11 + hd * yy12;
            float r02 = yy02 + dt * yy12 + hd * yy22;
            float r11 = yy11 + dt * yy12;
            float r12 = yy12 + dt * yy22;
            yy00 = r00 + dt * r01 + hd * r02;
            yy01 = r01 + dt * r02;
            yy02 = r02;
            yy11 = r11 + dt * r12;
            yy12 = r12;
            yy00 += gs3 * gs3; yy01 += gs3 * gs4; yy02 += gs3 * gs5;
            yy11 += gs4 * gs4; yy12 += gs4 * gs5; yy22 += gs5 * gs5;
        }
        {   // cross block c = A c A^T + gs_x gs_y^T (full 3x3)
            float q00 = c00 + dt * c10 + hd * c20;
            float q01 = c01 + dt * c11 + hd * c21;
            float q02 = c02 + dt * c12 + hd * c22;
            float q10 = c10 + dt * c20;
            float q11 = c11 + dt * c21;
            float q12 = c12 + dt * c22;
            c00 = q00 + dt * q01 + hd * q02;
            c01 = q01 + dt * q02;
            c02 = q02;
            c10 = q10 + dt * q11 + hd * q12;
            c11 = q11 + dt * q12;
            c12 = q12;
            float n20 = c20 + dt * c21 + hd * c22;
            float n21 = c21 + dt * c22;
            c20 = n20; c21 = n21;
            c00 += gs0 * gs3; c01 += gs0 * gs4; c02 += gs0 * gs5;
            c10 += gs1 * gs3; c11 += gs1 * gs4; c12 += gs1 * gs5;
            c20 += gs2 * gs3; c21 += gs2 * gs4; c22 += gs2 * gs5;
        }

        float sx = sqrtf(xx00), sy = sqrtf(yy00);
        float rho = c00 / (sx * sy);
        if (s == 0) {
            size_t o = ((size_t)tp * B + b) * 5u;
            out[o + 0] = X0;
            out[o + 1] = X3;
            out[o + 2] = sx;
            out[o + 3] = sy;
            out[o + 4] = rho;
        }
    }
}

extern "C" void kernel_launch(void* const* d_in, const int* in_sizes, int n_in,
                              void* d_out, int out_size, void* d_ws, size_t ws_size,
                              hipStream_t stream) {
    const int T = 16;
    const int B = in_sizes[0] / (2 * T);      // 32768
    const int len_pred = out_size / (5 * B);  // 25
    (void)d_ws; (void)ws_size; (void)n_in;

    const int grid = (B + EPB - 1) / EPB;     // one wave per 16 elements
    kalman_lstm<<<grid, BLK, 0, stream>>>(
        (const float*)d_in[0],  (const float*)d_in[1],  (const float*)d_in[2],
        (const float*)d_in[3],  (const float*)d_in[4],  (const float*)d_in[5],
        (const float*)d_in[6],  (const float*)d_in[7],  (const float*)d_in[8],
        (const float*)d_in[9],  (const float*)d_in[10], (const float*)d_in[11],
        (const float*)d_in[12], (const float*)d_in[13], (const float*)d_in[14],
        (const float*)d_in[15], (const float*)d_in[16], (const float*)d_in[17],
        (float*)d_out, B, len_pred);
}